// Round 1
// baseline (233.154 us; speedup 1.0000x reference)
//
#include <hip/hip_runtime.h>

typedef unsigned short u16;
typedef unsigned int u32;
typedef float f32x4 __attribute__((ext_vector_type(4)));
typedef short bf16x8 __attribute__((ext_vector_type(8)));

#define U_M 0.8f
#define L_M 0.45f
#define U_A 110.0f
#define L_A 10.0f
#define LAMBDA_G 35.0f
#define SCALEF 64.0f

__device__ __forceinline__ u16 f2bf(float f) {
  u32 u = __builtin_bit_cast(u32, f);
  u32 r = (u + 0x7fffu + ((u >> 16) & 1u)) >> 16;
  return (u16)r;
}

// ---- normalize rows of x, store bf16. one wave per row, 4 rows/block ----
__global__ void xnorm_kernel(const float* __restrict__ x, u16* __restrict__ xn, int K) {
  int row = blockIdx.x * 4 + (threadIdx.x >> 6);
  int l = threadIdx.x & 63;
  const float4* p = reinterpret_cast<const float4*>(x + (size_t)row * K) + l * 2;
  float4 a = p[0], b = p[1];
  float s = a.x*a.x + a.y*a.y + a.z*a.z + a.w*a.w
          + b.x*b.x + b.y*b.y + b.z*b.z + b.w*b.w;
  #pragma unroll
  for (int m = 32; m >= 1; m >>= 1) s += __shfl_xor(s, m);
  float inv = rsqrtf(fmaxf(s, 1e-24f));
  u32 q0 = (u32)f2bf(a.x*inv) | ((u32)f2bf(a.y*inv) << 16);
  u32 q1 = (u32)f2bf(a.z*inv) | ((u32)f2bf(a.w*inv) << 16);
  u32 q2 = (u32)f2bf(b.x*inv) | ((u32)f2bf(b.y*inv) << 16);
  u32 q3 = (u32)f2bf(b.z*inv) | ((u32)f2bf(b.w*inv) << 16);
  *reinterpret_cast<uint4*>(xn + (size_t)row * K + l * 8) = make_uint4(q0, q1, q2, q3);
}

// ---- inverse row norms of W. one wave per row, 4 rows/block ----
__global__ void wnorm_kernel(const float* __restrict__ W, float* __restrict__ invw, int K) {
  int row = blockIdx.x * 4 + (threadIdx.x >> 6);
  int l = threadIdx.x & 63;
  const float4* p = reinterpret_cast<const float4*>(W + (size_t)row * K) + l * 2;
  float4 a = p[0], b = p[1];
  float s = a.x*a.x + a.y*a.y + a.z*a.z + a.w*a.w
          + b.x*b.x + b.y*b.y + b.z*b.z + b.w*b.w;
  #pragma unroll
  for (int m = 32; m >= 1; m >>= 1) s += __shfl_xor(s, m);
  if (l == 0) invw[row] = rsqrtf(fmaxf(s, 1e-24f));
}

// ---- f32-exact target-class cosine per sample ----
__global__ void tgt_kernel(const float* __restrict__ x, const float* __restrict__ W,
                           const int* __restrict__ labels, float* __restrict__ tgtcos, int K) {
  int b = blockIdx.x;
  int l = threadIdx.x;
  int lab = labels[b];
  int labc = lab < 0 ? 0 : lab;
  const float4* px = reinterpret_cast<const float4*>(x + (size_t)b * K) + l * 2;
  const float4* pw = reinterpret_cast<const float4*>(W + (size_t)labc * K) + l * 2;
  float4 a0 = px[0], a1 = px[1], w0 = pw[0], w1 = pw[1];
  float dot = a0.x*w0.x + a0.y*w0.y + a0.z*w0.z + a0.w*w0.w
            + a1.x*w1.x + a1.y*w1.y + a1.z*w1.z + a1.w*w1.w;
  float sx = a0.x*a0.x + a0.y*a0.y + a0.z*a0.z + a0.w*a0.w
           + a1.x*a1.x + a1.y*a1.y + a1.z*a1.z + a1.w*a1.w;
  float sw = w0.x*w0.x + w0.y*w0.y + w0.z*w0.z + w0.w*w0.w
           + w1.x*w1.x + w1.y*w1.y + w1.z*w1.z + w1.w*w1.w;
  #pragma unroll
  for (int m = 32; m >= 1; m >>= 1) {
    dot += __shfl_xor(dot, m);
    sx  += __shfl_xor(sx, m);
    sw  += __shfl_xor(sw, m);
  }
  if (l == 0) {
    float cv = dot * rsqrtf(fmaxf(sx, 1e-24f)) * rsqrtf(fmaxf(sw, 1e-24f));
    tgtcos[b] = fminf(fmaxf(cv, -1.f), 1.f);
  }
}

// ---- fused GEMM: partial sumexp(64*cos - 64) per (block, row), target zeroed ----
__global__ __launch_bounds__(256, 2) void gemm_fused(
    const u16* __restrict__ xn, const float* __restrict__ W,
    const float* __restrict__ invw, const int* __restrict__ labels,
    float* __restrict__ partials, int C, int K, int M) {
  __shared__ u16 sA[128 * 64];
  __shared__ u16 sB[128 * 64];
  __shared__ float bsum[2][128];
  __shared__ int slab[128];
  const int t = threadIdx.x;
  const int bn = blockIdx.x, bm = blockIdx.y;
  const int l = t & 63, wid = t >> 6;
  const int wm = wid >> 1, wn = wid & 1;
  const int n0 = bn * 128;
  if (t < 128) slab[t] = labels[bm * 128 + t];
  f32x4 acc[4][4] = {};
  const int nkt = K >> 6;
  for (int kt = 0; kt < nkt; ++kt) {
    const int k0 = kt << 6;
    // stage A tile (bf16 from ws): 128 rows x 64 k
    #pragma unroll
    for (int i = 0; i < 4; ++i) {
      int L = t + 256 * i;
      int r = L >> 3, c = L & 7;
      uint4 v = *reinterpret_cast<const uint4*>(xn + (size_t)(bm * 128 + r) * K + k0 + c * 8);
      *reinterpret_cast<uint4*>(sA + r * 64 + ((c ^ (r & 7)) * 8)) = v;
    }
    // stage B tile (f32 -> bf16): 128 rows x 64 k
    #pragma unroll
    for (int i = 0; i < 8; ++i) {
      int L = t + 256 * i;
      int r = L >> 4, c = L & 15;
      int grow = n0 + r; grow = grow < C ? grow : C - 1;
      float4 v = *reinterpret_cast<const float4*>(W + (size_t)grow * K + k0 + c * 4);
      uint2 p;
      p.x = (u32)f2bf(v.x) | ((u32)f2bf(v.y) << 16);
      p.y = (u32)f2bf(v.z) | ((u32)f2bf(v.w) << 16);
      *reinterpret_cast<uint2*>(sB + r * 64 + (((c >> 1) ^ (r & 7)) * 8) + (c & 1) * 4) = p;
    }
    __syncthreads();
    bf16x8 af[2][4], bfr[2][4];
    #pragma unroll
    for (int ks = 0; ks < 2; ++ks) {
      #pragma unroll
      for (int mi = 0; mi < 4; ++mi) {
        int row = wm * 64 + mi * 16 + (l & 15);
        int ch = ks * 4 + (l >> 4);
        af[ks][mi] = *reinterpret_cast<const bf16x8*>(sA + row * 64 + ((ch ^ (row & 7)) * 8));
      }
      #pragma unroll
      for (int ni = 0; ni < 4; ++ni) {
        int row = wn * 64 + ni * 16 + (l & 15);
        int ch = ks * 4 + (l >> 4);
        bfr[ks][ni] = *reinterpret_cast<const bf16x8*>(sB + row * 64 + ((ch ^ (row & 7)) * 8));
      }
    }
    #pragma unroll
    for (int ks = 0; ks < 2; ++ks)
      #pragma unroll
      for (int mi = 0; mi < 4; ++mi)
        #pragma unroll
        for (int ni = 0; ni < 4; ++ni)
          acc[mi][ni] = __builtin_amdgcn_mfma_f32_16x16x32_bf16(af[ks][mi], bfr[ks][ni], acc[mi][ni], 0, 0, 0);
    __syncthreads();
  }
  // epilogue: cos -> exp(64 cos - 64), zero target column, per-row reduce
  float iw[4]; int colv[4];
  #pragma unroll
  for (int ni = 0; ni < 4; ++ni) {
    int col = n0 + wn * 64 + ni * 16 + (l & 15);
    colv[ni] = col;
    iw[ni] = invw[col < C ? col : (C - 1)];
  }
  #pragma unroll
  for (int mi = 0; mi < 4; ++mi) {
    #pragma unroll
    for (int rg = 0; rg < 4; ++rg) {
      int row_l = wm * 64 + mi * 16 + ((l >> 4) << 2) + rg;
      int labr = slab[row_l];
      float rs = 0.f;
      #pragma unroll
      for (int ni = 0; ni < 4; ++ni) {
        float cv = acc[mi][ni][rg] * iw[ni];
        cv = fminf(fmaxf(cv, -1.f), 1.f);
        float e = __expf(SCALEF * cv - SCALEF);
        bool keep = (colv[ni] < C) && (colv[ni] != labr);
        rs += keep ? e : 0.f;
      }
      rs += __shfl_xor(rs, 1);
      rs += __shfl_xor(rs, 2);
      rs += __shfl_xor(rs, 4);
      rs += __shfl_xor(rs, 8);
      if ((l & 15) == 0) bsum[wn][row_l] = rs;
    }
  }
  __syncthreads();
  if (t < 128) {
    partials[(size_t)bn * M + bm * 128 + t] = bsum[0][t] + bsum[1][t];
  }
}

// ---- deterministic reduction of partials over N-blocks ----
__global__ void rowreduce_kernel(const float* __restrict__ partials, float* __restrict__ rowsum,
                                 int NBN, int M) {
  int b = blockIdx.x, t = threadIdx.x;
  float s = 0.f;
  for (int i = t; i < NBN; i += 256) s += partials[(size_t)i * M + b];
  __shared__ float sh[256];
  sh[t] = s; __syncthreads();
  for (int off = 128; off >= 1; off >>= 1) {
    if (t < off) sh[t] += sh[t + off];
    __syncthreads();
  }
  if (t == 0) rowsum[b] = sh[0];
}

// ---- final: per-sample nll + G-loss, single block ----
__global__ void final_kernel(const float* __restrict__ rowsum, const float* __restrict__ tgtcos,
                             const float* __restrict__ x_norm, const int* __restrict__ labels,
                             float* __restrict__ out, int Bn) {
  int t = threadIdx.x;
  float nll = 0.f, g = 0.f, vld = 0.f;
  if (t < Bn) {
    float a = x_norm[t];
    g = a * (1.0f / (U_A * U_A)) + 1.0f / a;
    int lab = labels[t];
    bool valid = (lab != -1);
    if (valid) {
      float ct = tgtcos[t];
      float margin = ((U_M - L_M) / (U_A - L_A)) * (a - L_A) + L_M;
      float theta = acosf(ct) + margin;
      float tl = SCALEF * cosf(theta);
      float se = rowsum[t] + __expf(tl - SCALEF);
      float lse = SCALEF + logf(se);
      nll = lse - tl;
      vld = 1.f;
    }
  }
  __shared__ float s1[512], s2[512], s3[512];
  s1[t] = nll; s2[t] = g; s3[t] = vld;
  __syncthreads();
  for (int off = 256; off >= 1; off >>= 1) {
    if (t < off) { s1[t] += s1[t + off]; s2[t] += s2[t + off]; s3[t] += s3[t + off]; }
    __syncthreads();
  }
  if (t == 0) {
    float ce = s1[0] / fmaxf(s3[0], 1.f);
    out[0] = ce + LAMBDA_G * (s2[0] / (float)Bn);
  }
}

extern "C" void kernel_launch(void* const* d_in, const int* in_sizes, int n_in,
                              void* d_out, int out_size, void* d_ws, size_t ws_size,
                              hipStream_t stream) {
  const float* x      = (const float*)d_in[0];
  const float* x_norm = (const float*)d_in[1];
  const int*   labels = (const int*)d_in[2];
  const float* W      = (const float*)d_in[3];
  float* out = (float*)d_out;

  const int B = in_sizes[1];             // 512
  const int D = in_sizes[0] / B;         // 512
  const int C = in_sizes[3] / D;         // 100000
  const int NBN = (C + 127) / 128;       // 782

  char* ws = (char*)d_ws;
  u16*   xn      = (u16*)ws;                         // B*D*2      = 512 KiB
  float* invw    = (float*)(ws + 524288);            // C*4        = 400 KB
  float* tgtcos  = (float*)(ws + 924672);            // B*4
  float* rowsum  = (float*)(ws + 926720);            // B*4
  float* partials= (float*)(ws + 928768);            // NBN*B*4    = 1.6 MB

  hipLaunchKernelGGL(xnorm_kernel, dim3(B / 4), dim3(256), 0, stream, x, xn, D);
  hipLaunchKernelGGL(wnorm_kernel, dim3(C / 4), dim3(256), 0, stream, W, invw, D);
  hipLaunchKernelGGL(tgt_kernel, dim3(B), dim3(64), 0, stream, x, W, labels, tgtcos, D);
  hipLaunchKernelGGL(gemm_fused, dim3(NBN, B / 128), dim3(256), 0, stream,
                     xn, W, invw, labels, partials, C, D, B);
  hipLaunchKernelGGL(rowreduce_kernel, dim3(B), dim3(256), 0, stream, partials, rowsum, NBN, B);
  hipLaunchKernelGGL(final_kernel, dim3(1), dim3(B), 0, stream, rowsum, tgtcos, x_norm, labels, out, B);
}

// Round 2
// 130.861 us; speedup vs baseline: 1.7817x; 1.7817x over previous
//
#include <hip/hip_runtime.h>

typedef unsigned short u16;
typedef unsigned int u32;
typedef float f32x4 __attribute__((ext_vector_type(4)));
typedef short bf16x8 __attribute__((ext_vector_type(8)));

#define U_M 0.8f
#define L_M 0.45f
#define U_A 110.0f
#define L_A 10.0f
#define LAMBDA_G 35.0f
#define SCALEF 64.0f

__device__ __forceinline__ u16 f2bf(float f) {
  u32 u = __builtin_bit_cast(u32, f);
  u32 r = (u + 0x7fffu + ((u >> 16) & 1u)) >> 16;
  return (u16)r;
}

// ---- normalize rows of x, store bf16. one wave per row, 4 rows/block ----
__global__ void xnorm_kernel(const float* __restrict__ x, u16* __restrict__ xn, int K) {
  int row = blockIdx.x * 4 + (threadIdx.x >> 6);
  int l = threadIdx.x & 63;
  const float4* p = reinterpret_cast<const float4*>(x + (size_t)row * K) + l * 2;
  float4 a = p[0], b = p[1];
  float s = a.x*a.x + a.y*a.y + a.z*a.z + a.w*a.w
          + b.x*b.x + b.y*b.y + b.z*b.z + b.w*b.w;
  #pragma unroll
  for (int m = 32; m >= 1; m >>= 1) s += __shfl_xor(s, m);
  float inv = rsqrtf(fmaxf(s, 1e-24f));
  u32 q0 = (u32)f2bf(a.x*inv) | ((u32)f2bf(a.y*inv) << 16);
  u32 q1 = (u32)f2bf(a.z*inv) | ((u32)f2bf(a.w*inv) << 16);
  u32 q2 = (u32)f2bf(b.x*inv) | ((u32)f2bf(b.y*inv) << 16);
  u32 q3 = (u32)f2bf(b.z*inv) | ((u32)f2bf(b.w*inv) << 16);
  *reinterpret_cast<uint4*>(xn + (size_t)row * K + l * 8) = make_uint4(q0, q1, q2, q3);
}

// ---- fused: W row normalize -> bf16 (pre-scaled by 1/||w||). 4 rows/block ----
__global__ void wprep_kernel(const float* __restrict__ W, u16* __restrict__ wn, int K) {
  int row = blockIdx.x * 4 + (threadIdx.x >> 6);
  int l = threadIdx.x & 63;
  const float4* p = reinterpret_cast<const float4*>(W + (size_t)row * K) + l * 2;
  float4 a = p[0], b = p[1];
  float s = a.x*a.x + a.y*a.y + a.z*a.z + a.w*a.w
          + b.x*b.x + b.y*b.y + b.z*b.z + b.w*b.w;
  #pragma unroll
  for (int m = 32; m >= 1; m >>= 1) s += __shfl_xor(s, m);
  float inv = rsqrtf(fmaxf(s, 1e-24f));
  u32 q0 = (u32)f2bf(a.x*inv) | ((u32)f2bf(a.y*inv) << 16);
  u32 q1 = (u32)f2bf(a.z*inv) | ((u32)f2bf(a.w*inv) << 16);
  u32 q2 = (u32)f2bf(b.x*inv) | ((u32)f2bf(b.y*inv) << 16);
  u32 q3 = (u32)f2bf(b.z*inv) | ((u32)f2bf(b.w*inv) << 16);
  *reinterpret_cast<uint4*>(wn + (size_t)row * K + l * 8) = make_uint4(q0, q1, q2, q3);
}

// ---- inverse row norms of W (fallback path only) ----
__global__ void wnorm_kernel(const float* __restrict__ W, float* __restrict__ invw, int K) {
  int row = blockIdx.x * 4 + (threadIdx.x >> 6);
  int l = threadIdx.x & 63;
  const float4* p = reinterpret_cast<const float4*>(W + (size_t)row * K) + l * 2;
  float4 a = p[0], b = p[1];
  float s = a.x*a.x + a.y*a.y + a.z*a.z + a.w*a.w
          + b.x*b.x + b.y*b.y + b.z*b.z + b.w*b.w;
  #pragma unroll
  for (int m = 32; m >= 1; m >>= 1) s += __shfl_xor(s, m);
  if (l == 0) invw[row] = rsqrtf(fmaxf(s, 1e-24f));
}

// ---- f32-exact target-class cosine per sample ----
__global__ void tgt_kernel(const float* __restrict__ x, const float* __restrict__ W,
                           const int* __restrict__ labels, float* __restrict__ tgtcos, int K) {
  int b = blockIdx.x;
  int l = threadIdx.x;
  int lab = labels[b];
  int labc = lab < 0 ? 0 : lab;
  const float4* px = reinterpret_cast<const float4*>(x + (size_t)b * K) + l * 2;
  const float4* pw = reinterpret_cast<const float4*>(W + (size_t)labc * K) + l * 2;
  float4 a0 = px[0], a1 = px[1], w0 = pw[0], w1 = pw[1];
  float dot = a0.x*w0.x + a0.y*w0.y + a0.z*w0.z + a0.w*w0.w
            + a1.x*w1.x + a1.y*w1.y + a1.z*w1.z + a1.w*w1.w;
  float sx = a0.x*a0.x + a0.y*a0.y + a0.z*a0.z + a0.w*a0.w
           + a1.x*a1.x + a1.y*a1.y + a1.z*a1.z + a1.w*a1.w;
  float sw = w0.x*w0.x + w0.y*w0.y + w0.z*w0.z + w0.w*w0.w
           + w1.x*w1.x + w1.y*w1.y + w1.z*w1.z + w1.w*w1.w;
  #pragma unroll
  for (int m = 32; m >= 1; m >>= 1) {
    dot += __shfl_xor(dot, m);
    sx  += __shfl_xor(sx, m);
    sw  += __shfl_xor(sw, m);
  }
  if (l == 0) {
    float cv = dot * rsqrtf(fmaxf(sx, 1e-24f)) * rsqrtf(fmaxf(sw, 1e-24f));
    tgtcos[b] = fminf(fmaxf(cv, -1.f), 1.f);
  }
}

// ---- fast GEMM: both operands pre-normalized bf16, global_load_lds staging ----
__global__ __launch_bounds__(256, 2) void gemm_bf16(
    const u16* __restrict__ xn, const u16* __restrict__ wn,
    const int* __restrict__ labels,
    float* __restrict__ partials, int C, int K, int M, int NBN) {
  __shared__ u16 sA[128 * 64];
  __shared__ u16 sB[128 * 64];
  __shared__ float bsum[2][128];
  __shared__ int slab[128];

  // XCD-bijective swizzle (m204), bm-fastest within a chunk
  int nwg = gridDim.x;
  int id = blockIdx.x;
  int q = nwg >> 3, r = nwg & 7;
  int xcd = id & 7, pos = id >> 3;
  int wg = (xcd < r ? xcd * (q + 1) : r * (q + 1) + (xcd - r) * q) + pos;
  const int bm = wg & 3, bn = wg >> 2;

  const int t = threadIdx.x;
  const int l = t & 63, wid = t >> 6;
  const int wm = wid >> 1, wn_ = wid & 1;
  const int n0 = bn * 128;
  if (t < 128) slab[t] = labels[bm * 128 + t];

  f32x4 acc[4][4] = {};
  const int nkt = K >> 6;
  for (int kt = 0; kt < nkt; ++kt) {
    const int k0 = kt << 6;
    // stage A: 128x64 bf16, linear LDS dest, source pre-swizzled (chunk ^ (row&7))
    #pragma unroll
    for (int i = 0; i < 4; ++i) {
      int L = i * 256 + t;
      int rr = L >> 3;
      int cs = (L & 7) ^ (rr & 7);
      const u16* src = xn + (size_t)(bm * 128 + rr) * K + k0 + cs * 8;
      __builtin_amdgcn_global_load_lds(
          (const __attribute__((address_space(1))) void*)src,
          (__attribute__((address_space(3))) void*)(sA + (size_t)(i * 256 + (t & 192)) * 8),
          16, 0, 0);
    }
    // stage B: 128x64 bf16 from normalized W
    #pragma unroll
    for (int i = 0; i < 4; ++i) {
      int L = i * 256 + t;
      int rr = L >> 3;
      int cs = (L & 7) ^ (rr & 7);
      int grow = n0 + rr; grow = grow < C ? grow : C - 1;
      const u16* src = wn + (size_t)grow * K + k0 + cs * 8;
      __builtin_amdgcn_global_load_lds(
          (const __attribute__((address_space(1))) void*)src,
          (__attribute__((address_space(3))) void*)(sB + (size_t)(i * 256 + (t & 192)) * 8),
          16, 0, 0);
    }
    __syncthreads();
    #pragma unroll
    for (int ks = 0; ks < 2; ++ks) {
      bf16x8 af[4], bfr[4];
      #pragma unroll
      for (int mi = 0; mi < 4; ++mi) {
        int row = wm * 64 + mi * 16 + (l & 15);
        int ch = ks * 4 + (l >> 4);
        af[mi] = *reinterpret_cast<const bf16x8*>(sA + row * 64 + ((ch ^ (row & 7)) * 8));
      }
      #pragma unroll
      for (int ni = 0; ni < 4; ++ni) {
        int row = wn_ * 64 + ni * 16 + (l & 15);
        int ch = ks * 4 + (l >> 4);
        bfr[ni] = *reinterpret_cast<const bf16x8*>(sB + row * 64 + ((ch ^ (row & 7)) * 8));
      }
      #pragma unroll
      for (int mi = 0; mi < 4; ++mi)
        #pragma unroll
        for (int ni = 0; ni < 4; ++ni)
          acc[mi][ni] = __builtin_amdgcn_mfma_f32_16x16x32_bf16(af[mi], bfr[ni], acc[mi][ni], 0, 0, 0);
    }
    __syncthreads();
  }
  // epilogue: exp(64*cos - 64), zero target column, per-row reduce
  int colv[4];
  #pragma unroll
  for (int ni = 0; ni < 4; ++ni) colv[ni] = n0 + wn_ * 64 + ni * 16 + (l & 15);
  #pragma unroll
  for (int mi = 0; mi < 4; ++mi) {
    #pragma unroll
    for (int rg = 0; rg < 4; ++rg) {
      int row_l = wm * 64 + mi * 16 + ((l >> 4) << 2) + rg;
      int labr = slab[row_l];
      float rs = 0.f;
      #pragma unroll
      for (int ni = 0; ni < 4; ++ni) {
        float cv = acc[mi][ni][rg];
        cv = fminf(fmaxf(cv, -1.f), 1.f);
        float e = __expf(SCALEF * cv - SCALEF);
        bool keep = (colv[ni] < C) && (colv[ni] != labr);
        rs += keep ? e : 0.f;
      }
      rs += __shfl_xor(rs, 1);
      rs += __shfl_xor(rs, 2);
      rs += __shfl_xor(rs, 4);
      rs += __shfl_xor(rs, 8);
      if ((l & 15) == 0) bsum[wn_][row_l] = rs;
    }
  }
  __syncthreads();
  if (t < 128) {
    partials[(size_t)bn * M + bm * 128 + t] = bsum[0][t] + bsum[1][t];
  }
}

// ---- fallback GEMM (round-1, f32 W + invw) ----
__global__ __launch_bounds__(256, 2) void gemm_fused(
    const u16* __restrict__ xn, const float* __restrict__ W,
    const float* __restrict__ invw, const int* __restrict__ labels,
    float* __restrict__ partials, int C, int K, int M) {
  __shared__ u16 sA[128 * 64];
  __shared__ u16 sB[128 * 64];
  __shared__ float bsum[2][128];
  __shared__ int slab[128];
  const int t = threadIdx.x;
  const int bn = blockIdx.x, bm = blockIdx.y;
  const int l = t & 63, wid = t >> 6;
  const int wm = wid >> 1, wn = wid & 1;
  const int n0 = bn * 128;
  if (t < 128) slab[t] = labels[bm * 128 + t];
  f32x4 acc[4][4] = {};
  const int nkt = K >> 6;
  for (int kt = 0; kt < nkt; ++kt) {
    const int k0 = kt << 6;
    #pragma unroll
    for (int i = 0; i < 4; ++i) {
      int L = t + 256 * i;
      int r = L >> 3, c = L & 7;
      uint4 v = *reinterpret_cast<const uint4*>(xn + (size_t)(bm * 128 + r) * K + k0 + c * 8);
      *reinterpret_cast<uint4*>(sA + r * 64 + ((c ^ (r & 7)) * 8)) = v;
    }
    #pragma unroll
    for (int i = 0; i < 8; ++i) {
      int L = t + 256 * i;
      int r = L >> 4, c = L & 15;
      int grow = n0 + r; grow = grow < C ? grow : C - 1;
      float4 v = *reinterpret_cast<const float4*>(W + (size_t)grow * K + k0 + c * 4);
      uint2 p;
      p.x = (u32)f2bf(v.x) | ((u32)f2bf(v.y) << 16);
      p.y = (u32)f2bf(v.z) | ((u32)f2bf(v.w) << 16);
      *reinterpret_cast<uint2*>(sB + r * 64 + (((c >> 1) ^ (r & 7)) * 8) + (c & 1) * 4) = p;
    }
    __syncthreads();
    bf16x8 af[2][4], bfr[2][4];
    #pragma unroll
    for (int ks = 0; ks < 2; ++ks) {
      #pragma unroll
      for (int mi = 0; mi < 4; ++mi) {
        int row = wm * 64 + mi * 16 + (l & 15);
        int ch = ks * 4 + (l >> 4);
        af[ks][mi] = *reinterpret_cast<const bf16x8*>(sA + row * 64 + ((ch ^ (row & 7)) * 8));
      }
      #pragma unroll
      for (int ni = 0; ni < 4; ++ni) {
        int row = wn * 64 + ni * 16 + (l & 15);
        int ch = ks * 4 + (l >> 4);
        bfr[ks][ni] = *reinterpret_cast<const bf16x8*>(sB + row * 64 + ((ch ^ (row & 7)) * 8));
      }
    }
    #pragma unroll
    for (int ks = 0; ks < 2; ++ks)
      #pragma unroll
      for (int mi = 0; mi < 4; ++mi)
        #pragma unroll
        for (int ni = 0; ni < 4; ++ni)
          acc[mi][ni] = __builtin_amdgcn_mfma_f32_16x16x32_bf16(af[ks][mi], bfr[ks][ni], acc[mi][ni], 0, 0, 0);
    __syncthreads();
  }
  float iw[4]; int colv[4];
  #pragma unroll
  for (int ni = 0; ni < 4; ++ni) {
    int col = n0 + wn * 64 + ni * 16 + (l & 15);
    colv[ni] = col;
    iw[ni] = invw[col < C ? col : (C - 1)];
  }
  #pragma unroll
  for (int mi = 0; mi < 4; ++mi) {
    #pragma unroll
    for (int rg = 0; rg < 4; ++rg) {
      int row_l = wm * 64 + mi * 16 + ((l >> 4) << 2) + rg;
      int labr = slab[row_l];
      float rs = 0.f;
      #pragma unroll
      for (int ni = 0; ni < 4; ++ni) {
        float cv = acc[mi][ni][rg] * iw[ni];
        cv = fminf(fmaxf(cv, -1.f), 1.f);
        float e = __expf(SCALEF * cv - SCALEF);
        bool keep = (colv[ni] < C) && (colv[ni] != labr);
        rs += keep ? e : 0.f;
      }
      rs += __shfl_xor(rs, 1);
      rs += __shfl_xor(rs, 2);
      rs += __shfl_xor(rs, 4);
      rs += __shfl_xor(rs, 8);
      if ((l & 15) == 0) bsum[wn][row_l] = rs;
    }
  }
  __syncthreads();
  if (t < 128) {
    partials[(size_t)bn * M + bm * 128 + t] = bsum[0][t] + bsum[1][t];
  }
}

// ---- deterministic reduction of partials over N-blocks ----
__global__ void rowreduce_kernel(const float* __restrict__ partials, float* __restrict__ rowsum,
                                 int NBN, int M) {
  int b = blockIdx.x, t = threadIdx.x;
  float s = 0.f;
  for (int i = t; i < NBN; i += 256) s += partials[(size_t)i * M + b];
  __shared__ float sh[256];
  sh[t] = s; __syncthreads();
  for (int off = 128; off >= 1; off >>= 1) {
    if (t < off) sh[t] += sh[t + off];
    __syncthreads();
  }
  if (t == 0) rowsum[b] = sh[0];
}

// ---- final: per-sample nll + G-loss, single block ----
__global__ void final_kernel(const float* __restrict__ rowsum, const float* __restrict__ tgtcos,
                             const float* __restrict__ x_norm, const int* __restrict__ labels,
                             float* __restrict__ out, int Bn) {
  int t = threadIdx.x;
  float nll = 0.f, g = 0.f, vld = 0.f;
  if (t < Bn) {
    float a = x_norm[t];
    g = a * (1.0f / (U_A * U_A)) + 1.0f / a;
    int lab = labels[t];
    bool valid = (lab != -1);
    if (valid) {
      float ct = tgtcos[t];
      float margin = ((U_M - L_M) / (U_A - L_A)) * (a - L_A) + L_M;
      float theta = acosf(ct) + margin;
      float tl = SCALEF * cosf(theta);
      float se = rowsum[t] + __expf(tl - SCALEF);
      float lse = SCALEF + logf(se);
      nll = lse - tl;
      vld = 1.f;
    }
  }
  __shared__ float s1[512], s2[512], s3[512];
  s1[t] = nll; s2[t] = g; s3[t] = vld;
  __syncthreads();
  for (int off = 256; off >= 1; off >>= 1) {
    if (t < off) { s1[t] += s1[t + off]; s2[t] += s2[t + off]; s3[t] += s3[t + off]; }
    __syncthreads();
  }
  if (t == 0) {
    float ce = s1[0] / fmaxf(s3[0], 1.f);
    out[0] = ce + LAMBDA_G * (s2[0] / (float)Bn);
  }
}

extern "C" void kernel_launch(void* const* d_in, const int* in_sizes, int n_in,
                              void* d_out, int out_size, void* d_ws, size_t ws_size,
                              hipStream_t stream) {
  const float* x      = (const float*)d_in[0];
  const float* x_norm = (const float*)d_in[1];
  const int*   labels = (const int*)d_in[2];
  const float* W      = (const float*)d_in[3];
  float* out = (float*)d_out;

  const int B = in_sizes[1];             // 512
  const int D = in_sizes[0] / B;         // 512
  const int C = in_sizes[3] / D;         // 100000
  const int NBN = (C + 127) / 128;       // 782

  char* ws = (char*)d_ws;
  size_t o_xn   = 0;
  size_t o_invw = o_xn + (size_t)B * D * 2;        // C*4 (fallback only)
  size_t o_tgt  = o_invw + (size_t)C * 4;
  size_t o_rows = o_tgt + (size_t)B * 4;
  size_t o_part = o_rows + (size_t)B * 4;
  size_t o_wn   = o_part + (size_t)NBN * B * 4;
  size_t need   = o_wn + (size_t)C * D * 2;

  u16*   xn       = (u16*)(ws + o_xn);
  float* invw     = (float*)(ws + o_invw);
  float* tgtcos   = (float*)(ws + o_tgt);
  float* rowsum   = (float*)(ws + o_rows);
  float* partials = (float*)(ws + o_part);
  u16*   wn       = (u16*)(ws + o_wn);

  hipLaunchKernelGGL(xnorm_kernel, dim3(B / 4), dim3(256), 0, stream, x, xn, D);
  hipLaunchKernelGGL(tgt_kernel, dim3(B), dim3(64), 0, stream, x, W, labels, tgtcos, D);

  if (ws_size >= need) {
    hipLaunchKernelGGL(wprep_kernel, dim3(C / 4), dim3(256), 0, stream, W, wn, D);
    hipLaunchKernelGGL(gemm_bf16, dim3(NBN * (B / 128)), dim3(256), 0, stream,
                       xn, wn, labels, partials, C, D, B, NBN);
  } else {
    hipLaunchKernelGGL(wnorm_kernel, dim3(C / 4), dim3(256), 0, stream, W, invw, D);
    hipLaunchKernelGGL(gemm_fused, dim3(NBN, B / 128), dim3(256), 0, stream,
                       xn, W, invw, labels, partials, C, D, B);
  }
  hipLaunchKernelGGL(rowreduce_kernel, dim3(B), dim3(256), 0, stream, partials, rowsum, NBN, B);
  hipLaunchKernelGGL(final_kernel, dim3(1), dim3(B), 0, stream, rowsum, tgtcos, x_norm, labels, out, B);
}

// Round 3
// 116.516 us; speedup vs baseline: 2.0011x; 1.1231x over previous
//
#include <hip/hip_runtime.h>

typedef unsigned short u16;
typedef unsigned int u32;
typedef float f32x4 __attribute__((ext_vector_type(4)));
typedef short bf16x8 __attribute__((ext_vector_type(8)));

#define U_M 0.8f
#define L_M 0.45f
#define U_A 110.0f
#define L_A 10.0f
#define LAMBDA_G 35.0f
#define SCALEF 64.0f

__device__ __forceinline__ u16 f2bf(float f) {
  u32 u = __builtin_bit_cast(u32, f);
  u32 r = (u + 0x7fffu + ((u >> 16) & 1u)) >> 16;
  return (u16)r;
}

__device__ __forceinline__ u32 cvtpk(float lo, float hi) {
  u32 r;
  asm("v_cvt_pk_bf16_f32 %0, %1, %2" : "=v"(r) : "v"(lo), "v"(hi));
  return r;
}

// ---- normalize rows of x, store bf16. one wave per row, 4 rows/block ----
__global__ void xnorm_kernel(const float* __restrict__ x, u16* __restrict__ xn, int K) {
  int row = blockIdx.x * 4 + (threadIdx.x >> 6);
  int l = threadIdx.x & 63;
  const float4* p = reinterpret_cast<const float4*>(x + (size_t)row * K) + l * 2;
  float4 a = p[0], b = p[1];
  float s = a.x*a.x + a.y*a.y + a.z*a.z + a.w*a.w
          + b.x*b.x + b.y*b.y + b.z*b.z + b.w*b.w;
  #pragma unroll
  for (int m = 32; m >= 1; m >>= 1) s += __shfl_xor(s, m);
  float inv = rsqrtf(fmaxf(s, 1e-24f));
  u32 q0 = (u32)f2bf(a.x*inv) | ((u32)f2bf(a.y*inv) << 16);
  u32 q1 = (u32)f2bf(a.z*inv) | ((u32)f2bf(a.w*inv) << 16);
  u32 q2 = (u32)f2bf(b.x*inv) | ((u32)f2bf(b.y*inv) << 16);
  u32 q3 = (u32)f2bf(b.z*inv) | ((u32)f2bf(b.w*inv) << 16);
  *reinterpret_cast<uint4*>(xn + (size_t)row * K + l * 8) = make_uint4(q0, q1, q2, q3);
}

// ---- f32-exact target-class cosine per sample ----
__global__ void tgt_kernel(const float* __restrict__ x, const float* __restrict__ W,
                           const int* __restrict__ labels, float* __restrict__ tgtcos, int K) {
  int b = blockIdx.x;
  int l = threadIdx.x;
  int lab = labels[b];
  int labc = lab < 0 ? 0 : lab;
  const float4* px = reinterpret_cast<const float4*>(x + (size_t)b * K) + l * 2;
  const float4* pw = reinterpret_cast<const float4*>(W + (size_t)labc * K) + l * 2;
  float4 a0 = px[0], a1 = px[1], w0 = pw[0], w1 = pw[1];
  float dot = a0.x*w0.x + a0.y*w0.y + a0.z*w0.z + a0.w*w0.w
            + a1.x*w1.x + a1.y*w1.y + a1.z*w1.z + a1.w*w1.w;
  float sx = a0.x*a0.x + a0.y*a0.y + a0.z*a0.z + a0.w*a0.w
           + a1.x*a1.x + a1.y*a1.y + a1.z*a1.z + a1.w*a1.w;
  float sw = w0.x*w0.x + w0.y*w0.y + w0.z*w0.z + w0.w*w0.w
           + w1.x*w1.x + w1.y*w1.y + w1.z*w1.z + w1.w*w1.w;
  #pragma unroll
  for (int m = 32; m >= 1; m >>= 1) {
    dot += __shfl_xor(dot, m);
    sx  += __shfl_xor(sx, m);
    sw  += __shfl_xor(sw, m);
  }
  if (l == 0) {
    float cv = dot * rsqrtf(fmaxf(sx, 1e-24f)) * rsqrtf(fmaxf(sw, 1e-24f));
    tgtcos[b] = fminf(fmaxf(cv, -1.f), 1.f);
  }
}

// ---- single-pass fused GEMM: W f32 read once; normalize+convert+sumsq in staging ----
__global__ __launch_bounds__(256, 2) void gemm_wf32(
    const u16* __restrict__ xn, const float* __restrict__ W,
    const int* __restrict__ labels,
    float* __restrict__ partials, int C, int K, int M) {
  __shared__ u16 sA[128 * 64];
  __shared__ u16 sB[128 * 64];
  __shared__ float bsum[2][128];
  __shared__ float sIw[128];
  __shared__ int slab[128];

  // XCD-bijective swizzle (m204), bm-fastest within a chunk
  int nwg = gridDim.x;
  int id = blockIdx.x;
  int q = nwg >> 3, r = nwg & 7;
  int xcd = id & 7, pos = id >> 3;
  int wg = (xcd < r ? xcd * (q + 1) : r * (q + 1) + (xcd - r) * q) + pos;
  const int bm = wg & 3, bn = wg >> 2;

  const int t = threadIdx.x;
  const int l = t & 63, wid = t >> 6;
  const int wm = wid >> 1, wn_ = wid & 1;
  const int n0 = bn * 128;
  if (t < 128) slab[t] = labels[bm * 128 + t];

  // B staging geometry: 4 threads per row, 2 passes (rows 0-63, 64-127)
  const int qq = t & 3;            // quarter within row: 16 f32 = 4 float4
  const int rbase = t >> 2;        // row within pass
  float ssq0 = 0.f, ssq1 = 0.f;

  f32x4 acc[4][4] = {};
  const int nkt = K >> 6;
  for (int kt = 0; kt < nkt; ++kt) {
    const int k0 = kt << 6;

    // --- issue B global loads first (f32, 64B contiguous per 4-lane group) ---
    float4 v0[4], v1[4];
    {
      int r0 = n0 + rbase;       r0 = r0 < C ? r0 : C - 1;
      int r1 = n0 + 64 + rbase;  r1 = r1 < C ? r1 : C - 1;
      const float4* p0 = reinterpret_cast<const float4*>(W + (size_t)r0 * K + k0 + qq * 16);
      const float4* p1 = reinterpret_cast<const float4*>(W + (size_t)r1 * K + k0 + qq * 16);
      #pragma unroll
      for (int j = 0; j < 4; ++j) v0[j] = p0[j];
      #pragma unroll
      for (int j = 0; j < 4; ++j) v1[j] = p1[j];
    }

    // --- stage A via global_load_lds (source pre-swizzled, LDS linear) ---
    #pragma unroll
    for (int i = 0; i < 4; ++i) {
      int L = i * 256 + t;
      int rr = L >> 3;
      int cs = (L & 7) ^ (rr & 7);
      const u16* src = xn + (size_t)(bm * 128 + rr) * K + k0 + cs * 8;
      __builtin_amdgcn_global_load_lds(
          (const __attribute__((address_space(1))) void*)src,
          (__attribute__((address_space(3))) void*)(sA + (size_t)(i * 256 + (t & 192)) * 8),
          16, 0, 0);
    }

    // --- convert B to bf16 + sumsq, swizzled LDS write ---
    #pragma unroll
    for (int pass = 0; pass < 2; ++pass) {
      const float4* v = pass ? v1 : v0;
      int rr = pass * 64 + rbase;
      float s = 0.f;
      u32 pk[8];
      #pragma unroll
      for (int j = 0; j < 4; ++j) {
        float4 f = v[j];
        s += f.x*f.x + f.y*f.y + f.z*f.z + f.w*f.w;
        pk[j*2]   = cvtpk(f.x, f.y);
        pk[j*2+1] = cvtpk(f.z, f.w);
      }
      if (pass) ssq1 += s; else ssq0 += s;
      int c0 = qq * 2;
      uint4 w0 = make_uint4(pk[0], pk[1], pk[2], pk[3]);
      uint4 w1 = make_uint4(pk[4], pk[5], pk[6], pk[7]);
      *reinterpret_cast<uint4*>(sB + rr * 64 + (((c0    ) ^ (rr & 7)) * 8)) = w0;
      *reinterpret_cast<uint4*>(sB + rr * 64 + (((c0 + 1) ^ (rr & 7)) * 8)) = w1;
    }

    __syncthreads();
    #pragma unroll
    for (int ks = 0; ks < 2; ++ks) {
      bf16x8 af[4], bfr[4];
      #pragma unroll
      for (int mi = 0; mi < 4; ++mi) {
        int row = wm * 64 + mi * 16 + (l & 15);
        int ch = ks * 4 + (l >> 4);
        af[mi] = *reinterpret_cast<const bf16x8*>(sA + row * 64 + ((ch ^ (row & 7)) * 8));
      }
      #pragma unroll
      for (int ni = 0; ni < 4; ++ni) {
        int row = wn_ * 64 + ni * 16 + (l & 15);
        int ch = ks * 4 + (l >> 4);
        bfr[ni] = *reinterpret_cast<const bf16x8*>(sB + row * 64 + ((ch ^ (row & 7)) * 8));
      }
      #pragma unroll
      for (int mi = 0; mi < 4; ++mi)
        #pragma unroll
        for (int ni = 0; ni < 4; ++ni)
          acc[mi][ni] = __builtin_amdgcn_mfma_f32_16x16x32_bf16(af[mi], bfr[ni], acc[mi][ni], 0, 0, 0);
    }
    __syncthreads();
  }

  // finalize inverse row norms of W tile (4-lane reduce, lanes share row)
  {
    float s0 = ssq0 + __shfl_xor(ssq0, 1);
    s0 += __shfl_xor(s0, 2);
    float s1 = ssq1 + __shfl_xor(ssq1, 1);
    s1 += __shfl_xor(s1, 2);
    if (qq == 0) {
      sIw[rbase]      = rsqrtf(fmaxf(s0, 1e-24f));
      sIw[64 + rbase] = rsqrtf(fmaxf(s1, 1e-24f));
    }
  }
  __syncthreads();

  // epilogue: cos -> exp(64 cos - 64), zero target column, per-row reduce
  float iw[4]; int colv[4];
  #pragma unroll
  for (int ni = 0; ni < 4; ++ni) {
    int cl = wn_ * 64 + ni * 16 + (l & 15);
    colv[ni] = n0 + cl;
    iw[ni] = sIw[cl];
  }
  #pragma unroll
  for (int mi = 0; mi < 4; ++mi) {
    #pragma unroll
    for (int rg = 0; rg < 4; ++rg) {
      int row_l = wm * 64 + mi * 16 + ((l >> 4) << 2) + rg;
      int labr = slab[row_l];
      float rs = 0.f;
      #pragma unroll
      for (int ni = 0; ni < 4; ++ni) {
        float cv = acc[mi][ni][rg] * iw[ni];
        cv = fminf(fmaxf(cv, -1.f), 1.f);
        float e = __expf(SCALEF * cv - SCALEF);
        bool keep = (colv[ni] < C) && (colv[ni] != labr);
        rs += keep ? e : 0.f;
      }
      rs += __shfl_xor(rs, 1);
      rs += __shfl_xor(rs, 2);
      rs += __shfl_xor(rs, 4);
      rs += __shfl_xor(rs, 8);
      if ((l & 15) == 0) bsum[wn_][row_l] = rs;
    }
  }
  __syncthreads();
  if (t < 128) {
    partials[(size_t)bn * M + bm * 128 + t] = bsum[0][t] + bsum[1][t];
  }
}

// ---- deterministic reduction of partials over N-blocks ----
__global__ void rowreduce_kernel(const float* __restrict__ partials, float* __restrict__ rowsum,
                                 int NBN, int M) {
  int b = blockIdx.x, t = threadIdx.x;
  float s = 0.f;
  for (int i = t; i < NBN; i += 256) s += partials[(size_t)i * M + b];
  __shared__ float sh[256];
  sh[t] = s; __syncthreads();
  for (int off = 128; off >= 1; off >>= 1) {
    if (t < off) sh[t] += sh[t + off];
    __syncthreads();
  }
  if (t == 0) rowsum[b] = sh[0];
}

// ---- final: per-sample nll + G-loss, single block ----
__global__ void final_kernel(const float* __restrict__ rowsum, const float* __restrict__ tgtcos,
                             const float* __restrict__ x_norm, const int* __restrict__ labels,
                             float* __restrict__ out, int Bn) {
  int t = threadIdx.x;
  float nll = 0.f, g = 0.f, vld = 0.f;
  if (t < Bn) {
    float a = x_norm[t];
    g = a * (1.0f / (U_A * U_A)) + 1.0f / a;
    int lab = labels[t];
    bool valid = (lab != -1);
    if (valid) {
      float ct = tgtcos[t];
      float margin = ((U_M - L_M) / (U_A - L_A)) * (a - L_A) + L_M;
      float theta = acosf(ct) + margin;
      float tl = SCALEF * cosf(theta);
      float se = rowsum[t] + __expf(tl - SCALEF);
      float lse = SCALEF + logf(se);
      nll = lse - tl;
      vld = 1.f;
    }
  }
  __shared__ float s1[512], s2[512], s3[512];
  s1[t] = nll; s2[t] = g; s3[t] = vld;
  __syncthreads();
  for (int off = 256; off >= 1; off >>= 1) {
    if (t < off) { s1[t] += s1[t + off]; s2[t] += s2[t + off]; s3[t] += s3[t + off]; }
    __syncthreads();
  }
  if (t == 0) {
    float ce = s1[0] / fmaxf(s3[0], 1.f);
    out[0] = ce + LAMBDA_G * (s2[0] / (float)Bn);
  }
}

extern "C" void kernel_launch(void* const* d_in, const int* in_sizes, int n_in,
                              void* d_out, int out_size, void* d_ws, size_t ws_size,
                              hipStream_t stream) {
  const float* x      = (const float*)d_in[0];
  const float* x_norm = (const float*)d_in[1];
  const int*   labels = (const int*)d_in[2];
  const float* W      = (const float*)d_in[3];
  float* out = (float*)d_out;

  const int B = in_sizes[1];             // 512
  const int D = in_sizes[0] / B;         // 512
  const int C = in_sizes[3] / D;         // 100000
  const int NBN = (C + 127) / 128;       // 782

  char* ws = (char*)d_ws;
  size_t o_xn   = 0;
  size_t o_tgt  = o_xn + (size_t)B * D * 2;
  size_t o_rows = o_tgt + (size_t)B * 4;
  size_t o_part = o_rows + (size_t)B * 4;

  u16*   xn       = (u16*)(ws + o_xn);
  float* tgtcos   = (float*)(ws + o_tgt);
  float* rowsum   = (float*)(ws + o_rows);
  float* partials = (float*)(ws + o_part);

  hipLaunchKernelGGL(xnorm_kernel, dim3(B / 4), dim3(256), 0, stream, x, xn, D);
  hipLaunchKernelGGL(tgt_kernel, dim3(B), dim3(64), 0, stream, x, W, labels, tgtcos, D);
  hipLaunchKernelGGL(gemm_wf32, dim3(NBN * (B / 128)), dim3(256), 0, stream,
                     xn, W, labels, partials, C, D, B);
  hipLaunchKernelGGL(rowreduce_kernel, dim3(B), dim3(256), 0, stream, partials, rowsum, NBN, B);
  hipLaunchKernelGGL(final_kernel, dim3(1), dim3(B), 0, stream, rowsum, tgtcos, x_norm, labels, out, B);
}